// Round 17
// baseline (112.991 us; speedup 1.0000x reference)
//
#include <hip/hip_runtime.h>
#include <math.h>

// out[b,i,j,f] = min_{di,dj,c} ( x[b,i+di,j+dj,c] - W[di,dj,c,f] )
// x: (16,128,128,16) f32, W: (3,3,16,32) f32, out: (16,126,126,32) f32
//
// R17: the never-run fair ILP test -- 2 output cols per thread AT FULL
// occupancy. 128-thread blocks (2 waves): 32f x 2ch x 2jt, 2 cols each
// -> 4 cols/block; TI=16, grid 32x8x16 = 4096 blocks = 16 blocks/CU
// (workgroup limit) x 2 waves = 32 waves/CU, single clean round.
// (R14's 2-col ran at 24 waves/CU -- confounded.) Per body: 4 broadcast
// ds_read_b128 -> 2x69 packed-fp16 insts (reads/output x2/3, 2x wider
// dep chains between LDS waits). LROW=56 halves (112B row stride, bank
// shift 28) kills stage-write conflicts. W in regs, shfl merge, static
// bounds with by=7 overlap-recompute (idempotent), direct reads + unroll
// 2 to hold VGPR < 64 (R14 killer).

#define TI 16           // output rows per block; by=7 starts at 110 (overlap)
#define TROWS (TI + 2)  // input rows per tile (18)
#define LROW 56         // tile row stride in halves (48 used + 8 pad)

typedef _Float16 h2 __attribute__((ext_vector_type(2)));

__device__ __forceinline__ h2 hmin2(h2 a, h2 b) {
    return __builtin_elementwise_min(a, b);  // v_pk_min_f16
}

__device__ __forceinline__ h2 pkrtz(float a, float b) {
    auto r = __builtin_amdgcn_cvt_pkrtz(a, b);  // v_cvt_pkrtz_f16_f32
    return *reinterpret_cast<h2*>(&r);
}

// min over 12 half2 of (pr[dj][q] - w[dj][q]); pr points at 3 consecutive
// 16B col-spans (SSA consume, no copies).
__device__ __forceinline__ h2 rowmin3(const float4* pr, const h2 w[3][4]) {
    h2 t[12];
#pragma unroll
    for (int dj = 0; dj < 3; ++dj) {
        const h2* p = reinterpret_cast<const h2*>(&pr[dj]);
#pragma unroll
        for (int q = 0; q < 4; ++q)
            t[dj * 4 + q] = p[q] - w[dj][q];  // v_pk_add_f16 neg
    }
#pragma unroll
    for (int k = 0; k < 6; ++k) t[k] = hmin2(t[k], t[k + 6]);
    t[0] = hmin2(t[0], t[3]);
    t[1] = hmin2(t[1], t[4]);
    t[2] = hmin2(t[2], t[5]);
    return hmin2(hmin2(t[0], t[1]), t[2]);
}

__global__ __launch_bounds__(128) void erosion_kernel(
    const float* __restrict__ x, const float* __restrict__ Wt,
    float* __restrict__ out)
{
    // [ch:2][row:18][LROW=56 halves] = 4032 B (16 blocks/CU -> 63 KB/CU)
    __shared__ _Float16 tile[2 * TROWS * LROW];

    const int tid = threadIdx.x;
    const int f  = tid & 31;
    const int ch = (tid >> 5) & 1;   // channel half: 0 -> c 0..7, 1 -> c 8..15
    const int jt = (tid >> 6) & 1;   // wave id = col-pair (wave-uniform)
    const int b  = blockIdx.z;
    const int by = blockIdx.y;
    const int i0 = (by == 7) ? 110 : by * TI;  // 0,16,..,96,110 (110-111 overlap)
    const int jb = blockIdx.x * 4;   // block covers output cols jb..jb+3
    const int j0 = jb + 2 * jt;      // this thread's first output col
    const bool w0 = (ch == 0) && (j0     < 126);
    const bool w1 = (ch == 0) && (j0 + 1 < 126);

    // ---- stage x tile: fp32 -> fp16 LDS (18 rows x 6 cols x 2 ch) ----
    // chunk t (t < 216): r = t/12, k = t%12 -> col = jb + k/2, ch2 = k&1.
    {
        const float* xg = x + (size_t)b * (128 * 128 * 16);
        auto stage = [&](int t) {
            int r   = t / 12;
            int k   = t % 12;
            int cc  = k >> 1;          // 0..5 tile column
            int ch2 = k & 1;
            int col = min(jb + cc, 127);  // clamp: feeds never-stored outputs only
            const float* src = xg + ((size_t)(i0 + r) * 128 + col) * 16 + ch2 * 8;
            float4 lo = *reinterpret_cast<const float4*>(src);
            float4 hi = *reinterpret_cast<const float4*>(src + 4);
            h2 o[4] = { pkrtz(lo.x, lo.y), pkrtz(lo.z, lo.w),
                        pkrtz(hi.x, hi.y), pkrtz(hi.z, hi.w) };
            *reinterpret_cast<float4*>(
                &tile[ch2 * (TROWS * LROW) + r * LROW + cc * 8]) =
                *reinterpret_cast<float4*>(o);
        };
        stage(tid);
        if (tid < TROWS * 12 - 128) stage(tid + 128);  // 88 extra chunks
    }

    // ---- W slice in registers (R12-proven; R13: never put W in LDS) ----
    h2 wh[3][3][4];
#pragma unroll
    for (int di = 0; di < 3; ++di)
#pragma unroll
        for (int dj = 0; dj < 3; ++dj)
#pragma unroll
            for (int q = 0; q < 4; ++q) {
                int p = di * 3 + dj;
                float a = Wt[(p * 16 + ch * 8 + 2 * q) * 32 + f];
                float c = Wt[(p * 16 + ch * 8 + 2 * q + 1) * 32 + f];
                wh[di][dj][q] = pkrtz(a, c);
            }

    __syncthreads();

    // thread's leftmost tile-local col = 2*jt; its 4 spans: 2jt .. 2jt+3
    const _Float16* lb = &tile[ch * (TROWS * LROW) + (2 * jt) * 8];
    float* op = out + (((size_t)b * 126 + i0) * 126 + j0) * 32 + f;

    const _Float16 HINF = (_Float16)__builtin_huge_valf();
    h2 accB0 = {HINF, HINF}, accB1 = {HINF, HINF};
    h2 accC0 = {HINF, HINF}, accC1 = {HINF, HINF};

    auto body = [&](int r, bool do_store) {
        // 4 broadcast ds_read_b128 (direct, short-lived -> low VGPR)
        float4 sp[4];
#pragma unroll
        for (int s = 0; s < 4; ++s)
            sp[s] = *reinterpret_cast<const float4*>(lb + r * LROW + s * 8);

        // col j0 uses spans 0..2, col j0+1 uses spans 1..3
        h2 n00 = rowmin3(&sp[0], wh[0]);
        h2 n01 = rowmin3(&sp[0], wh[1]);
        h2 n02 = rowmin3(&sp[0], wh[2]);
        h2 n10 = rowmin3(&sp[1], wh[0]);
        h2 n11 = rowmin3(&sp[1], wh[1]);
        h2 n12 = rowmin3(&sp[1], wh[2]);

        h2 fin0 = hmin2(accC0, n02);  // output row r-2 complete (col j0)
        h2 fin1 = hmin2(accC1, n12);  //                          (col j0+1)
        accC0 = hmin2(accB0, n01);  accB0 = n00;
        accC1 = hmin2(accB1, n11);  accB1 = n10;

        if (do_store) {
            _Float16 a0 = fin0[0], c0 = fin0[1];
            _Float16 a1 = fin1[0], c1 = fin1[1];
            float v0 = (float)(a0 < c0 ? a0 : c0);
            float v1 = (float)(a1 < c1 ? a1 : c1);
            v0 = fminf(v0, __shfl_xor(v0, 32));  // merge c-halves (lanes tid^32)
            v1 = fminf(v1, __shfl_xor(v1, 32));
            float* row = op + (size_t)(r - 2) * (126 * 32);
            if (w0) row[0]  = v0;
            if (w1) row[32] = v1;
        }
    };

    body(0, false);
    body(1, false);
#pragma unroll 2
    for (int r = 2; r < TROWS; ++r)   // r = 2..17, static bound
        body(r, true);
}

extern "C" void kernel_launch(void* const* d_in, const int* in_sizes, int n_in,
                              void* d_out, int out_size, void* d_ws, size_t ws_size,
                              hipStream_t stream) {
    const float* x  = (const float*)d_in[0];  // 16*128*128*16
    const float* Wt = (const float*)d_in[1];  // 3*3*16*32
    float* out = (float*)d_out;               // 16*126*126*32

    dim3 grid(32, 8, 16);   // 4096 blocks x 2 waves = 32 waves/CU, one round
    dim3 block(128);
    erosion_kernel<<<grid, block, 0, stream>>>(x, Wt, out);
}

// Round 18
// 108.856 us; speedup vs baseline: 1.0380x; 1.0380x over previous
//
#include <hip/hip_runtime.h>
#include <math.h>

// out[b,i,j,f] = min_{di,dj,c} ( x[b,i+di,j+dj,c] - W[di,dj,c,f] )
// x: (16,128,128,16) f32, W: (3,3,16,32) f32, out: (16,126,126,32) f32
//
// R18 = R12 verbatim (session best: 50.3us dispatch, absmax 0.03125).
// Final consolidation after the R13-R17 exploration all landed flat or
// worse: this is the empirical plateau of the packed-fp16 min-plus
// structure on gfx950 at HIP source level. Remaining gap to the ~22us
// VALU-issue floor is in-order-issue stall not addressable without
// instruction-level scheduling control (cf. m97 GEMM plateau, m131-m141).
//
// Structure: single fused kernel (no d_ws -- graph-replay safe), fp32
// tile -> pkrtz -> fp16 LDS, W in 36 h2 regs, rolling 3-row window with
// depth-1 LDS prefetch, per-thread row results to vmbuf (fire-and-forget
// b16), packed merge epilogue (4 outputs/task via 2 ds_read_b64 +
// 2 v_pk_min_f16 + float4 store). Grid 3072 (32x6x16), TI=21.

#define TI 21           // output rows per block; 126 = 21*6
#define TROWS (TI + 2)  // input rows per tile (23)
#define LROW 64         // tile row stride in halves (48 used + pad)

typedef _Float16 h2 __attribute__((ext_vector_type(2)));

__device__ __forceinline__ h2 hmin2(h2 a, h2 b) {
    return __builtin_elementwise_min(a, b);  // v_pk_min_f16
}

__device__ __forceinline__ h2 pkrtz(float a, float b) {
    auto r = __builtin_amdgcn_cvt_pkrtz(a, b);  // v_cvt_pkrtz_f16_f32
    return *reinterpret_cast<h2*>(&r);
}

// min over 12 half2 of (pr[k] - w[k]) for one weight row di; consumes the
// prefetch registers directly (SSA, no copies).
__device__ __forceinline__ h2 rowmin3(const float4* pr, const h2 w[3][4]) {
    h2 t[12];
#pragma unroll
    for (int dj = 0; dj < 3; ++dj) {
        const h2* p = reinterpret_cast<const h2*>(&pr[dj]);
#pragma unroll
        for (int q = 0; q < 4; ++q)
            t[dj * 4 + q] = p[q] - w[dj][q];  // v_pk_add_f16 neg
    }
#pragma unroll
    for (int k = 0; k < 6; ++k) t[k] = hmin2(t[k], t[k + 6]);
    t[0] = hmin2(t[0], t[3]);
    t[1] = hmin2(t[1], t[4]);
    t[2] = hmin2(t[2], t[5]);
    return hmin2(hmin2(t[0], t[1]), t[2]);
}

__global__ __launch_bounds__(256) void erosion_kernel(
    const float* __restrict__ x, const float* __restrict__ Wt,
    float* __restrict__ out)
{
    __shared__ _Float16 tile[2 * TROWS * LROW];  // 5888 B
    __shared__ _Float16 vmbuf[TI * 256];         // 10752 B

    const int tid = threadIdx.x;
    const int f  = tid & 31;
    const int ch = (tid >> 5) & 1;   // channel half: 0 -> c 0..7, 1 -> c 8..15
    const int jt = tid >> 6;         // column in block (wave-uniform)
    const int b  = blockIdx.z;
    const int i0 = blockIdx.y * TI;
    const int jb = blockIdx.x * 4;

    // ---- fused stage: fp32 tile -> fp16 LDS (23 rows x 6 cols x 2 ch) ----
    // chunk t (t < 276): r = t/12, k = t%12 -> col = jb + k/2, ch2 = k&1.
    {
        const float* xg = x + (size_t)b * (128 * 128 * 16);
        auto stage = [&](int t) {
            int r   = t / 12;
            int k   = t % 12;
            int cc  = k >> 1;          // 0..5 tile column
            int ch2 = k & 1;
            int col = min(jb + cc, 127);  // clamp: feeds never-stored outputs only
            const float* src = xg + ((size_t)(i0 + r) * 128 + col) * 16 + ch2 * 8;
            float4 lo = *reinterpret_cast<const float4*>(src);
            float4 hi = *reinterpret_cast<const float4*>(src + 4);
            h2 o[4] = { pkrtz(lo.x, lo.y), pkrtz(lo.z, lo.w),
                        pkrtz(hi.x, hi.y), pkrtz(hi.z, hi.w) };
            *reinterpret_cast<float4*>(
                &tile[ch2 * (TROWS * LROW) + r * LROW + cc * 8]) =
                *reinterpret_cast<float4*>(o);
        };
        stage(tid);
        if (tid < TROWS * 12 - 256) stage(tid + 256);  // 20 extra chunks
    }

    // wh[di][dj][q] = { W[di,dj, ch*8+2q, f], W[di,dj, ch*8+2q+1, f] } as fp16
    h2 wh[3][3][4];
#pragma unroll
    for (int di = 0; di < 3; ++di)
#pragma unroll
        for (int dj = 0; dj < 3; ++dj)
#pragma unroll
            for (int q = 0; q < 4; ++q) {
                int p = di * 3 + dj;
                float a = Wt[(p * 16 + ch * 8 + 2 * q) * 32 + f];
                float c = Wt[(p * 16 + ch * 8 + 2 * q + 1) * 32 + f];
                wh[di][dj][q] = pkrtz(a, c);
            }

    __syncthreads();

    const _Float16* lb = &tile[ch * (TROWS * LROW) + jt * 8];  // row 0, col jt

    const _Float16 HINF = (_Float16)__builtin_huge_valf();
    h2 accB = {HINF, HINF};  // partial min for output row r-1
    h2 accC = {HINF, HINF};  // partial min for output row r-2

    // depth-1 prefetch regs: current row's 3 col-spans (16B each)
    float4 pre[3];
#pragma unroll
    for (int dj = 0; dj < 3; ++dj)
        pre[dj] = *reinterpret_cast<const float4*>(lb + dj * 8);

    auto body = [&](int r, bool do_prefetch, bool do_vm) {
        h2 n0 = rowmin3(pre, wh[0]);
        h2 n1 = rowmin3(pre, wh[1]);
        h2 n2 = rowmin3(pre, wh[2]);

        if (do_prefetch) {
            const _Float16* ln = lb + (r + 1) * LROW;
#pragma unroll
            for (int dj = 0; dj < 3; ++dj)
                pre[dj] = *reinterpret_cast<const float4*>(ln + dj * 8);
        }

        h2 fin2 = hmin2(accC, n2);  // output row r-2 complete
        accC = hmin2(accB, n1);
        accB = n0;

        if (do_vm) {
            _Float16 a = fin2[0], c = fin2[1];
            _Float16 vm = a < c ? a : c;          // v_min_f16
            vmbuf[(r - 2) * 256 + tid] = vm;      // b16 write, no consumer wait
        }
    };

    body(0, true, false);
    body(1, true, false);
#pragma unroll 2
    for (int r = 2; r < TROWS - 1; ++r)   // r = 2..21
        body(r, true, true);
    body(TROWS - 1, false, true);         // r = 22, no prefetch

    __syncthreads();

    // ---- packed merge epilogue: 4 outputs per task ----
    // task t (t < TI*32): row = t>>5, k = t&31, col = k>>3, q = k&7.
    // partials: ch0 at vmbuf[row*256 + col*64 + 4q..+3], ch1 at +32.
    {
        float* outb = out + (size_t)b * (126 * 126 * 32);
        auto merge = [&](int t) {
            int row = t >> 5;
            int k   = t & 31;
            int col = k >> 3;
            int q   = k & 7;
            int jj  = jb + col;
            const _Float16* base = &vmbuf[row * 256 + col * 64 + q * 4];
            h2 a[2], c[2];
            *reinterpret_cast<double*>(a) = *reinterpret_cast<const double*>(base);
            *reinterpret_cast<double*>(c) = *reinterpret_cast<const double*>(base + 32);
            h2 m0 = hmin2(a[0], c[0]);
            h2 m1 = hmin2(a[1], c[1]);
            float4 o = { (float)m0[0], (float)m0[1], (float)m1[0], (float)m1[1] };
            if (jj < 126)
                *reinterpret_cast<float4*>(
                    &outb[((size_t)(i0 + row) * 126 + jj) * 32 + q * 4]) = o;
        };
        merge(tid);
        merge(tid + 256);
        if (tid < TI * 32 - 512) merge(tid + 512);  // 160 extra tasks
    }
}

extern "C" void kernel_launch(void* const* d_in, const int* in_sizes, int n_in,
                              void* d_out, int out_size, void* d_ws, size_t ws_size,
                              hipStream_t stream) {
    const float* x  = (const float*)d_in[0];  // 16*128*128*16
    const float* Wt = (const float*)d_in[1];  // 3*3*16*32
    float* out = (float*)d_out;               // 16*126*126*32

    dim3 grid(32, 6, 16);   // 3072 blocks (empirically best across R5-R17)
    dim3 block(256);
    erosion_kernel<<<grid, block, 0, stream>>>(x, Wt, out);
}